// Round 7
// baseline (85.142 us; speedup 1.0000x reference)
//
#include <hip/hip_runtime.h>
#include <hip/hip_fp16.h>

#define R_    1024
#define B_    4
#define C_    256
#define H_    64
#define W_    64
#define HW_   4096
#define PHW_  49
#define GREC  16      // f32 dwords per bin geometry record (64 B)
#define LROWF 258     // fixup LDS row halves (256 + 2 pad; 516B stride -> odd dword stride)
#define SLACKH 2048   // halves of zeroed slack after fTh (covers worst dx overrun)

__device__ __forceinline__ void cell_w(float start, float end, float s, float& g0, float& g1) {
    float y0 = fmaxf(start, s);
    float yl = fmaxf(fminf(end, s + 1.0f), y0);
    float a  = y0 - s;
    float la = yl - s;
    g0 = la - 0.5f * la * la - a + 0.5f * a * a;
    g1 = 0.5f * la * la - 0.5f * a * a;
}

__device__ __forceinline__ float4 h4_to_f4(uint2 u) {
    __half2 a = *reinterpret_cast<__half2*>(&u.x);
    __half2 b = *reinterpret_cast<__half2*>(&u.y);
    float2 fa = __half22float2(a);
    float2 fb = __half22float2(b);
    return make_float4(fa.x, fa.y, fb.x, fb.y);
}

// ---- prep: transpose (B,C,H,W) f32 -> (B,H*W,C) f16 [0..4095]
//            + ROI sort & slack-zero [4096] + geometry [4097..4292] ----
__global__ __launch_bounds__(256) void prep(const float* __restrict__ in,
                                            __half* __restrict__ fTh,
                                            const float* __restrict__ rois,
                                            int* __restrict__ perm,
                                            float* __restrict__ geom) {
    int bid = blockIdx.x;
    if (bid < 4096) {
        __shared__ float tile[32][33];
        int b   = bid >> 10;
        int rem = bid & 1023;
        int c0  = (rem >> 7) * 32;   // 8 channel tiles
        int p0  = (rem & 127) * 32;  // 128 p tiles
        int tx  = threadIdx.x & 31;
        int ty  = threadIdx.x >> 5;
        const float* src = in + (size_t)b * C_ * HW_;
#pragma unroll
        for (int i = 0; i < 32; i += 8)
            tile[ty + i][tx] = src[(size_t)(c0 + ty + i) * HW_ + (p0 + tx)];
        __syncthreads();
        __half2* dsth = (__half2*)(fTh + (size_t)b * HW_ * C_);
#pragma unroll
        for (int i = 0; i < 2; ++i) {
            int idx = threadIdx.x + i * 256;
            int py  = idx >> 4;      // 0..31
            int cp  = idx & 15;      // 0..15 channel pairs
            float lo = tile[cp * 2][py];
            float hi = tile[cp * 2 + 1][py];
            dsth[(size_t)(p0 + py) * (C_ / 2) + (c0 >> 1) + cp] = __floats2half2_rn(lo, hi);
        }
        return;
    }
    if (bid == 4096) {
        if (threadIdx.x >= 64) {
            // zero the slack region so unconditional dx-overrun loads are benign
            for (int j = threadIdx.x - 64; j < SLACKH; j += 192)
                fTh[(size_t)B_ * HW_ * C_ + j] = __half(0.0f);
            return;
        }
        // 1 wave: ballot-based stable counting sort by (batch, y-band). Deterministic.
        int lane = threadIdx.x;
        unsigned long long below = (1ull << lane) - 1ull;
        int key[16];
#pragma unroll
        for (int i = 0; i < 16; ++i) {
            int idx = i * 64 + lane;
            const float* roi = rois + idx * 5;
            int b = (int)roi[0];
            float yc = (roi[2] + roi[4]) * 0.5f * 0.0625f;
            int yb = min(3, max(0, (int)(yc * 0.0625f)));
            key[i] = b * 4 + yb;
        }
        int cnt[16];
#pragma unroll
        for (int k = 0; k < 16; ++k) cnt[k] = 0;
        for (int i = 0; i < 16; ++i)
#pragma unroll
            for (int k = 0; k < 16; ++k)
                cnt[k] += __popcll(__ballot(key[i] == k));
        int off[16]; int acc = 0;
#pragma unroll
        for (int k = 0; k < 16; ++k) { off[k] = acc; acc += cnt[k]; }
        for (int i = 0; i < 16; ++i) {
#pragma unroll
            for (int k = 0; k < 16; ++k) {
                unsigned long long m = __ballot(key[i] == k);
                if (key[i] == k)
                    perm[off[k] + __popcll(m & below)] = i * 64 + lane;
                off[k] += __popcll(m);
            }
        }
        return;
    }
    // geometry records
    int i = (bid - 4097) * 256 + threadIdx.x;   // 0..50175 exactly
    int r  = i / PHW_;
    int k  = i - r * PHW_;
    int ph = k / 7, pw = k - ph * 7;
    const float* roi = rois + r * 5;
    int bb = (int)roi[0];
    float x1 = roi[1] * 0.0625f, y1 = roi[2] * 0.0625f;
    float x2 = roi[3] * 0.0625f, y2 = roi[4] * 0.0625f;
    float rw = fmaxf(x2 - x1, 0.0f), rh = fmaxf(y2 - y1, 0.0f);
    float bw = rw / 7.0f, bh = rh / 7.0f;
    float win = bw * bh;
    float rec[GREC];
#pragma unroll
    for (int t = 0; t < GREC; ++t) rec[t] = 0.0f;
    if (win > 0.0f) {
        float ws = x1 + bw * (float)pw, we = ws + bw;
        float hs = y1 + bh * (float)ph, he = hs + bh;
        float s0w = floorf(ws), s0h = floorf(hs);
        int w0 = (int)s0w, h0 = (int)s0h;   // >= 0 for this input range
        float wy[7], wx[7];
#pragma unroll
        for (int t = 0; t < 7; ++t) { wy[t] = 0.0f; wx[t] = 0.0f; }
#pragma unroll
        for (int o = 0; o < 6; ++o) {
            float g0, g1;
            cell_w(hs, he, s0h + (float)o, g0, g1);
            wy[o] += g0; wy[o + 1] += g1;
            cell_w(ws, we, s0w + (float)o, g0, g1);
            wx[o] += g0; wx[o + 1] += g1;
        }
        int npy = min(7, max(0, (int)ceilf(he - s0h + 1.0f)));
        int npx = min(7, max(0, (int)ceilf(we - s0w + 1.0f)));
        npy = max(0, min(npy, H_ - h0));
        npx = max(0, min(npx, W_ - w0));
        // zero weights beyond the clipped counts (unconditional-dx relies on this)
#pragma unroll
        for (int t = 0; t < 7; ++t) {
            if (t >= npx) wx[t] = 0.0f;
            if (t >= npy) wy[t] = 0.0f;
        }
        float invwin = 1.0f / win;
#pragma unroll
        for (int t = 0; t < 7; ++t) { rec[t] = wy[t] * invwin; rec[7 + t] = wx[t]; }
        rec[14] = __int_as_float(h0 | (w0 << 8) | (npy << 16) | (npx << 24));
    }
    rec[15] = __int_as_float(bb);
    float4* gp = (float4*)(geom + (size_t)i * GREC);
    gp[0] = make_float4(rec[0],  rec[1],  rec[2],  rec[3]);
    gp[1] = make_float4(rec[4],  rec[5],  rec[6],  rec[7]);
    gp[2] = make_float4(rec[8],  rec[9],  rec[10], rec[11]);
    gp[3] = make_float4(rec[12], rec[13], rec[14], rec[15]);
}

// ---- compute: one wave per bin; 7 unconditional dx loads in flight; f16 gathers ----
__global__ __launch_bounds__(512) void prroi_bins(const __half* __restrict__ fTh,
                                                  const int* __restrict__ perm,
                                                  const float* __restrict__ geom,
                                                  __half* __restrict__ scr) {
    int bid  = blockIdx.x;                       // 6272 blocks
    int spos = (bid & 7) * 784 + (bid >> 3);     // XCD x owns sorted-bin chunk
    int wid  = threadIdx.x >> 6;
    int lane = threadIdx.x & 63;
    int bin  = __builtin_amdgcn_readfirstlane(spos * 8 + wid);
    int rs   = bin / PHW_;
    int k    = bin - rs * PHW_;
    int r    = __builtin_amdgcn_readfirstlane(perm[rs]);

    const float4* g = (const float4*)(geom + ((size_t)r * PHW_ + k) * GREC);
    float4 q0 = g[0], q1 = g[1], q2 = g[2], q3 = g[3];
    float wy[7] = {q0.x, q0.y, q0.z, q0.w, q1.x, q1.y, q1.z};
    float wx[7] = {q1.w, q2.x, q2.y, q2.z, q2.w, q3.x, q3.y};
    int pk  = __float_as_int(q3.z);
    int h0  = pk & 0xff;
    int w0  = (pk >> 8)  & 0xff;
    int npy = (pk >> 16) & 0xff;
    int bb  = __float_as_int(q3.w);

    const __half* fr = fTh + (((size_t)bb * HW_) + (h0 * W_ + w0)) * C_ + lane * 4;
    float ax = 0.0f, ay = 0.0f, az = 0.0f, aw = 0.0f;
#pragma unroll
    for (int dy = 0; dy < 7; ++dy) {
        if (dy < npy) {                          // wave-uniform (SGPR compare)
            const __half* rp = fr + dy * (W_ * C_);
            // 7 independent 8B loads issued together -> latency amortized
            uint2 v0 = *(const uint2*)(rp);
            uint2 v1 = *(const uint2*)(rp + C_);
            uint2 v2 = *(const uint2*)(rp + 2 * C_);
            uint2 v3 = *(const uint2*)(rp + 3 * C_);
            uint2 v4 = *(const uint2*)(rp + 4 * C_);
            uint2 v5 = *(const uint2*)(rp + 5 * C_);
            uint2 v6 = *(const uint2*)(rp + 6 * C_);
            float rx = 0.0f, ry = 0.0f, rz = 0.0f, rw = 0.0f;
#define ACC4(V, G) { float4 f_ = h4_to_f4(V); rx = fmaf(G, f_.x, rx); ry = fmaf(G, f_.y, ry); \
                     rz = fmaf(G, f_.z, rz); rw = fmaf(G, f_.w, rw); }
            ACC4(v0, wx[0]); ACC4(v1, wx[1]); ACC4(v2, wx[2]); ACC4(v3, wx[3]);
            ACC4(v4, wx[4]); ACC4(v5, wx[5]); ACC4(v6, wx[6]);
#undef ACC4
            float gy = wy[dy];
            ax = fmaf(gy, rx, ax);
            ay = fmaf(gy, ry, ay);
            az = fmaf(gy, rz, az);
            aw = fmaf(gy, rw, aw);
        }
    }
    __half2 lo = __floats2half2_rn(ax, ay);
    __half2 hi = __floats2half2_rn(az, aw);
    __half2* d = (__half2*)(scr + ((size_t)r * PHW_ + k) * C_ + lane * 4);
    d[0] = lo;
    d[1] = hi;
}

// ---- fixup: per-ROI [k][c] f16 -> [c][k] f32 through padded LDS; XCD-matched swizzle ----
__global__ __launch_bounds__(256) void fixup(const int* __restrict__ perm,
                                             const __half* __restrict__ scr,
                                             float* __restrict__ out) {
    __shared__ __align__(4) __half lds_h[PHW_ * LROWF];
    int bid  = blockIdx.x;
    int spos = ((bid & 7) << 7) | (bid >> 3);   // same sorted chunk -> same XCD as producer
    int r    = perm[spos];
    const unsigned int* src = (const unsigned int*)(scr + (size_t)r * PHW_ * C_);
    for (int j = threadIdx.x; j < PHW_ * (C_ / 2); j += 256) {
        int row = j >> 7;
        int col = j & 127;
        *(unsigned int*)&lds_h[row * LROWF + col * 2] = src[j];
    }
    __syncthreads();
    float* outr = out + (size_t)r * (C_ * PHW_);
#pragma unroll 4
    for (int j = threadIdx.x; j < C_ * PHW_; j += 256) {
        int c = j / PHW_;
        int k = j - c * PHW_;
        outr[j] = __half2float(lds_h[k * LROWF + c]);
    }
}

// ---- fallback: original layout, no workspace ----
__global__ __launch_bounds__(256) void prroi_pool_direct(const float* __restrict__ f,
                                                         const float* __restrict__ rois,
                                                         float* __restrict__ out) {
    int bin = blockIdx.x;
    int r  = bin / PHW_;
    int k  = bin - r * PHW_;
    int ph = k / 7;
    int pw = k - ph * 7;
    int c = threadIdx.x;

    const float* roi = rois + r * 5;
    int bb = (int)roi[0];
    float x1 = roi[1] * 0.0625f, y1 = roi[2] * 0.0625f;
    float x2 = roi[3] * 0.0625f, y2 = roi[4] * 0.0625f;
    float rw = fmaxf(x2 - x1, 0.0f), rh = fmaxf(y2 - y1, 0.0f);
    float bw = rw / 7.0f, bh = rh / 7.0f;
    float win = bw * bh;
    size_t oidx = ((size_t)r * C_ + c) * PHW_ + k;
    if (!(win > 0.0f)) { out[oidx] = 0.0f; return; }

    float ws = x1 + bw * (float)pw, we = ws + bw;
    float hs = y1 + bh * (float)ph, he = hs + bh;
    float s0w = floorf(ws), s0h = floorf(hs);
    int w0 = (int)s0w, h0 = (int)s0h;
    float wy[7], wx[7];
#pragma unroll
    for (int t = 0; t < 7; ++t) { wy[t] = 0.0f; wx[t] = 0.0f; }
#pragma unroll
    for (int o = 0; o < 6; ++o) {
        float g0, g1;
        cell_w(hs, he, s0h + (float)o, g0, g1);
        wy[o] += g0; wy[o + 1] += g1;
        cell_w(ws, we, s0w + (float)o, g0, g1);
        wx[o] += g0; wx[o + 1] += g1;
    }
    int npy = min(7, max(0, (int)ceilf(he - s0h + 1.0f)));
    int npx = min(7, max(0, (int)ceilf(we - s0w + 1.0f)));
    npy = max(0, min(npy, H_ - h0));
    npx = max(0, min(npx, W_ - w0));

    const float* fbc = f + ((size_t)bb * C_ + c) * (H_ * W_);
    float acc = 0.0f;
#pragma unroll
    for (int dy = 0; dy < 7; ++dy) {
        if (dy < npy) {
            float row = 0.0f;
#pragma unroll
            for (int dx = 0; dx < 7; ++dx) {
                if (dx < npx)
                    row = fmaf(wx[dx], fbc[(h0 + dy) * W_ + (w0 + dx)], row);
            }
            acc = fmaf(wy[dy], row, acc);
        }
    }
    out[oidx] = acc / win;
}

extern "C" void kernel_launch(void* const* d_in, const int* in_sizes, int n_in,
                              void* d_out, int out_size, void* d_ws, size_t ws_size,
                              hipStream_t stream) {
    const float* feat = (const float*)d_in[0];
    const float* rois = (const float*)d_in[1];
    float* out = (float*)d_out;

    const size_t fth_b  = (size_t)B_ * HW_ * C_ * sizeof(__half);    //  8,388,608
    const size_t slack_b = (size_t)SLACKH * sizeof(__half);          //      4,096
    const size_t perm_b = (size_t)R_ * sizeof(int);                  //      4,096
    const size_t geom_b = (size_t)R_ * PHW_ * GREC * sizeof(float);  //  3,211,264
    const size_t scr_b  = (size_t)R_ * PHW_ * C_ * sizeof(__half);   // 25,690,112

    if (ws_size >= fth_b + slack_b + perm_b + geom_b + scr_b) {
        __half* fTh  = (__half*)d_ws;
        int*    perm = (int*)((char*)d_ws + fth_b + slack_b);
        float*  geom = (float*)((char*)d_ws + fth_b + slack_b + perm_b);
        __half* scr  = (__half*)((char*)d_ws + fth_b + slack_b + perm_b + geom_b);
        prep<<<4293, 256, 0, stream>>>(feat, fTh, rois, perm, geom);
        prroi_bins<<<(R_ * PHW_) / 8, 512, 0, stream>>>(fTh, perm, geom, scr);
        fixup<<<R_, 256, 0, stream>>>(perm, scr, out);
    } else {
        prroi_pool_direct<<<R_ * PHW_, 256, 0, stream>>>(feat, rois, out);
    }
}

// Round 8
// 84.906 us; speedup vs baseline: 1.0028x; 1.0028x over previous
//
#include <hip/hip_runtime.h>
#include <hip/hip_fp16.h>

#define R_    1024
#define B_    4
#define C_    256
#define H_    64
#define W_    64
#define HW_   4096
#define PHW_  49
#define GREC  16      // f32 dwords per bin geometry record (64 B)
#define LROWF 258     // fixup LDS row halves (256 + 2 pad)
#define SLACKH 2048   // halves of zeroed slack after fTh (guards edge-clamp overrun)

__device__ __forceinline__ void cell_w(float start, float end, float s, float& g0, float& g1) {
    float y0 = fmaxf(start, s);
    float yl = fmaxf(fminf(end, s + 1.0f), y0);
    float a  = y0 - s;
    float la = yl - s;
    g0 = la - 0.5f * la * la - a + 0.5f * a * a;
    g1 = 0.5f * la * la - 0.5f * a * a;
}

__device__ __forceinline__ float4 h4_to_f4(uint2 u) {
    __half2 a = *reinterpret_cast<__half2*>(&u.x);
    __half2 b = *reinterpret_cast<__half2*>(&u.y);
    float2 fa = __half22float2(a);
    float2 fb = __half22float2(b);
    return make_float4(fa.x, fa.y, fb.x, fb.y);
}

// ---- prep: transpose (B,C,H,W) f32 -> (B,H*W,C) f16 [0..4095]
//            + ROI sort & slack-zero [4096] + geometry [4097..4292] ----
__global__ __launch_bounds__(256) void prep(const float* __restrict__ in,
                                            __half* __restrict__ fTh,
                                            const float* __restrict__ rois,
                                            int* __restrict__ perm,
                                            float* __restrict__ geom) {
    int bid = blockIdx.x;
    if (bid < 4096) {
        __shared__ float tile[32][33];
        int b   = bid >> 10;
        int rem = bid & 1023;
        int c0  = (rem >> 7) * 32;   // 8 channel tiles
        int p0  = (rem & 127) * 32;  // 128 p tiles
        int tx  = threadIdx.x & 31;
        int ty  = threadIdx.x >> 5;
        const float* src = in + (size_t)b * C_ * HW_;
#pragma unroll
        for (int i = 0; i < 32; i += 8)
            tile[ty + i][tx] = src[(size_t)(c0 + ty + i) * HW_ + (p0 + tx)];
        __syncthreads();
        __half2* dsth = (__half2*)(fTh + (size_t)b * HW_ * C_);
#pragma unroll
        for (int i = 0; i < 2; ++i) {
            int idx = threadIdx.x + i * 256;
            int py  = idx >> 4;      // 0..31
            int cp  = idx & 15;      // 0..15 channel pairs
            float lo = tile[cp * 2][py];
            float hi = tile[cp * 2 + 1][py];
            dsth[(size_t)(p0 + py) * (C_ / 2) + (c0 >> 1) + cp] = __floats2half2_rn(lo, hi);
        }
        return;
    }
    if (bid == 4096) {
        if (threadIdx.x >= 64) {
            for (int j = threadIdx.x - 64; j < SLACKH; j += 192)
                fTh[(size_t)B_ * HW_ * C_ + j] = __half(0.0f);
            return;
        }
        // 1 wave: ballot-based stable counting sort by (batch, y-band). Deterministic.
        int lane = threadIdx.x;
        unsigned long long below = (1ull << lane) - 1ull;
        int key[16];
#pragma unroll
        for (int i = 0; i < 16; ++i) {
            int idx = i * 64 + lane;
            const float* roi = rois + idx * 5;
            int b = (int)roi[0];
            float yc = (roi[2] + roi[4]) * 0.5f * 0.0625f;
            int yb = min(3, max(0, (int)(yc * 0.0625f)));
            key[i] = b * 4 + yb;
        }
        int cnt[16];
#pragma unroll
        for (int k = 0; k < 16; ++k) cnt[k] = 0;
        for (int i = 0; i < 16; ++i)
#pragma unroll
            for (int k = 0; k < 16; ++k)
                cnt[k] += __popcll(__ballot(key[i] == k));
        int off[16]; int acc = 0;
#pragma unroll
        for (int k = 0; k < 16; ++k) { off[k] = acc; acc += cnt[k]; }
        for (int i = 0; i < 16; ++i) {
#pragma unroll
            for (int k = 0; k < 16; ++k) {
                unsigned long long m = __ballot(key[i] == k);
                if (key[i] == k)
                    perm[off[k] + __popcll(m & below)] = i * 64 + lane;
                off[k] += __popcll(m);
            }
        }
        return;
    }
    // geometry records
    int i = (bid - 4097) * 256 + threadIdx.x;   // 0..50175 exactly
    int r  = i / PHW_;
    int k  = i - r * PHW_;
    int ph = k / 7, pw = k - ph * 7;
    const float* roi = rois + r * 5;
    int bb = (int)roi[0];
    float x1 = roi[1] * 0.0625f, y1 = roi[2] * 0.0625f;
    float x2 = roi[3] * 0.0625f, y2 = roi[4] * 0.0625f;
    float rw = fmaxf(x2 - x1, 0.0f), rh = fmaxf(y2 - y1, 0.0f);
    float bw = rw / 7.0f, bh = rh / 7.0f;
    float win = bw * bh;
    float rec[GREC];
#pragma unroll
    for (int t = 0; t < GREC; ++t) rec[t] = 0.0f;
    if (win > 0.0f) {
        float ws = x1 + bw * (float)pw, we = ws + bw;
        float hs = y1 + bh * (float)ph, he = hs + bh;
        float s0w = floorf(ws), s0h = floorf(hs);
        int w0 = (int)s0w, h0 = (int)s0h;   // >= 0 for this input range
        float wy[7], wx[7];
#pragma unroll
        for (int t = 0; t < 7; ++t) { wy[t] = 0.0f; wx[t] = 0.0f; }
#pragma unroll
        for (int o = 0; o < 6; ++o) {
            float g0, g1;
            cell_w(hs, he, s0h + (float)o, g0, g1);
            wy[o] += g0; wy[o + 1] += g1;
            cell_w(ws, we, s0w + (float)o, g0, g1);
            wx[o] += g0; wx[o + 1] += g1;
        }
        int npy = min(7, max(0, (int)ceilf(he - s0h + 1.0f)));
        int npx = min(7, max(0, (int)ceilf(we - s0w + 1.0f)));
        npy = max(0, min(npy, H_ - h0));
        npx = max(0, min(npx, W_ - w0));
        // zero weights beyond clipped counts (clamped unconditional-dx relies on this)
#pragma unroll
        for (int t = 0; t < 7; ++t) {
            if (t >= npx) wx[t] = 0.0f;
            if (t >= npy) wy[t] = 0.0f;
        }
        float invwin = 1.0f / win;
#pragma unroll
        for (int t = 0; t < 7; ++t) { rec[t] = wy[t] * invwin; rec[7 + t] = wx[t]; }
        rec[14] = __int_as_float(h0 | (w0 << 8) | (npy << 16) | (npx << 24));
    }
    rec[15] = __int_as_float(bb);
    float4* gp = (float4*)(geom + (size_t)i * GREC);
    gp[0] = make_float4(rec[0],  rec[1],  rec[2],  rec[3]);
    gp[1] = make_float4(rec[4],  rec[5],  rec[6],  rec[7]);
    gp[2] = make_float4(rec[8],  rec[9],  rec[10], rec[11]);
    gp[3] = make_float4(rec[12], rec[13], rec[14], rec[15]);
}

// ---- compute: one wave per bin; 7 batched dx loads with edge-clamped offsets ----
__global__ __launch_bounds__(512) void prroi_bins(const __half* __restrict__ fTh,
                                                  const int* __restrict__ perm,
                                                  const float* __restrict__ geom,
                                                  __half* __restrict__ scr) {
    int bid  = blockIdx.x;                       // 6272 blocks
    int spos = (bid & 7) * 784 + (bid >> 3);     // XCD x owns sorted-bin chunk
    int wid  = threadIdx.x >> 6;
    int lane = threadIdx.x & 63;
    int bin  = __builtin_amdgcn_readfirstlane(spos * 8 + wid);
    int rs   = bin / PHW_;
    int k    = bin - rs * PHW_;
    int r    = __builtin_amdgcn_readfirstlane(perm[rs]);

    const float4* g = (const float4*)(geom + ((size_t)r * PHW_ + k) * GREC);
    float4 q0 = g[0], q1 = g[1], q2 = g[2], q3 = g[3];
    float wy[7] = {q0.x, q0.y, q0.z, q0.w, q1.x, q1.y, q1.z};
    float wx[7] = {q1.w, q2.x, q2.y, q2.z, q2.w, q3.x, q3.y};
    int pk  = __float_as_int(q3.z);
    int h0  = pk & 0xff;
    int w0  = (pk >> 8)  & 0xff;
    int npy = (pk >> 16) & 0xff;
    int npx = (pk >> 24) & 0xff;
    int bb  = __float_as_int(q3.w);
    int npxm1 = max(npx - 1, 0);
    // wave-uniform clamped column offsets: loads past the window re-hit the same line (L1)
    int o1 = min(1, npxm1) * C_;
    int o2 = min(2, npxm1) * C_;
    int o3 = min(3, npxm1) * C_;
    int o4 = min(4, npxm1) * C_;
    int o5 = min(5, npxm1) * C_;
    int o6 = min(6, npxm1) * C_;

    const __half* fr = fTh + (((size_t)bb * HW_) + (h0 * W_ + w0)) * C_ + lane * 4;
    float ax = 0.0f, ay = 0.0f, az = 0.0f, aw = 0.0f;
#pragma unroll
    for (int dy = 0; dy < 7; ++dy) {
        if (dy < npy) {                          // wave-uniform (SGPR compare)
            const __half* rp = fr + dy * (W_ * C_);
            uint2 v0 = *(const uint2*)(rp);
            uint2 v1 = *(const uint2*)(rp + o1);
            uint2 v2 = *(const uint2*)(rp + o2);
            uint2 v3 = *(const uint2*)(rp + o3);
            uint2 v4 = *(const uint2*)(rp + o4);
            uint2 v5 = *(const uint2*)(rp + o5);
            uint2 v6 = *(const uint2*)(rp + o6);
            float rx = 0.0f, ry = 0.0f, rz = 0.0f, rw = 0.0f;
#define ACC4(V, G) { float4 f_ = h4_to_f4(V); rx = fmaf(G, f_.x, rx); ry = fmaf(G, f_.y, ry); \
                     rz = fmaf(G, f_.z, rz); rw = fmaf(G, f_.w, rw); }
            ACC4(v0, wx[0]); ACC4(v1, wx[1]); ACC4(v2, wx[2]); ACC4(v3, wx[3]);
            ACC4(v4, wx[4]); ACC4(v5, wx[5]); ACC4(v6, wx[6]);
#undef ACC4
            float gy = wy[dy];
            ax = fmaf(gy, rx, ax);
            ay = fmaf(gy, ry, ay);
            az = fmaf(gy, rz, az);
            aw = fmaf(gy, rw, aw);
        }
    }
    union { __half2 h2[2]; uint2 u; } pkst;
    pkst.h2[0] = __floats2half2_rn(ax, ay);
    pkst.h2[1] = __floats2half2_rn(az, aw);
    *(uint2*)(scr + ((size_t)r * PHW_ + k) * C_ + lane * 4) = pkst.u;
}

// ---- fixup: per-ROI [k][c] f16 -> [c][k] f32 through padded LDS; XCD-matched ----
__global__ __launch_bounds__(256) void fixup(const int* __restrict__ perm,
                                             const __half* __restrict__ scr,
                                             float* __restrict__ out) {
    __shared__ __align__(4) __half lds_h[PHW_ * LROWF];
    int bid  = blockIdx.x;
    int spos = ((bid & 7) << 7) | (bid >> 3);   // same sorted chunk -> same XCD as producer
    int r    = perm[spos];
    const unsigned int* src = (const unsigned int*)(scr + (size_t)r * PHW_ * C_);
    for (int j = threadIdx.x; j < PHW_ * (C_ / 2); j += 256) {
        int row = j >> 7;
        int col = j & 127;
        *(unsigned int*)&lds_h[row * LROWF + col * 2] = src[j];
    }
    __syncthreads();
    float* outr = out + (size_t)r * (C_ * PHW_);
#pragma unroll 4
    for (int j = threadIdx.x; j < C_ * PHW_; j += 256) {
        int c = j / PHW_;
        int k = j - c * PHW_;
        outr[j] = __half2float(lds_h[k * LROWF + c]);
    }
}

// ---- fallback: original layout, no workspace ----
__global__ __launch_bounds__(256) void prroi_pool_direct(const float* __restrict__ f,
                                                         const float* __restrict__ rois,
                                                         float* __restrict__ out) {
    int bin = blockIdx.x;
    int r  = bin / PHW_;
    int k  = bin - r * PHW_;
    int ph = k / 7;
    int pw = k - ph * 7;
    int c = threadIdx.x;

    const float* roi = rois + r * 5;
    int bb = (int)roi[0];
    float x1 = roi[1] * 0.0625f, y1 = roi[2] * 0.0625f;
    float x2 = roi[3] * 0.0625f, y2 = roi[4] * 0.0625f;
    float rw = fmaxf(x2 - x1, 0.0f), rh = fmaxf(y2 - y1, 0.0f);
    float bw = rw / 7.0f, bh = rh / 7.0f;
    float win = bw * bh;
    size_t oidx = ((size_t)r * C_ + c) * PHW_ + k;
    if (!(win > 0.0f)) { out[oidx] = 0.0f; return; }

    float ws = x1 + bw * (float)pw, we = ws + bw;
    float hs = y1 + bh * (float)ph, he = hs + bh;
    float s0w = floorf(ws), s0h = floorf(hs);
    int w0 = (int)s0w, h0 = (int)s0h;
    float wy[7], wx[7];
#pragma unroll
    for (int t = 0; t < 7; ++t) { wy[t] = 0.0f; wx[t] = 0.0f; }
#pragma unroll
    for (int o = 0; o < 6; ++o) {
        float g0, g1;
        cell_w(hs, he, s0h + (float)o, g0, g1);
        wy[o] += g0; wy[o + 1] += g1;
        cell_w(ws, we, s0w + (float)o, g0, g1);
        wx[o] += g0; wx[o + 1] += g1;
    }
    int npy = min(7, max(0, (int)ceilf(he - s0h + 1.0f)));
    int npx = min(7, max(0, (int)ceilf(we - s0w + 1.0f)));
    npy = max(0, min(npy, H_ - h0));
    npx = max(0, min(npx, W_ - w0));

    const float* fbc = f + ((size_t)bb * C_ + c) * (H_ * W_);
    float acc = 0.0f;
#pragma unroll
    for (int dy = 0; dy < 7; ++dy) {
        if (dy < npy) {
            float row = 0.0f;
#pragma unroll
            for (int dx = 0; dx < 7; ++dx) {
                if (dx < npx)
                    row = fmaf(wx[dx], fbc[(h0 + dy) * W_ + (w0 + dx)], row);
            }
            acc = fmaf(wy[dy], row, acc);
        }
    }
    out[oidx] = acc / win;
}

extern "C" void kernel_launch(void* const* d_in, const int* in_sizes, int n_in,
                              void* d_out, int out_size, void* d_ws, size_t ws_size,
                              hipStream_t stream) {
    const float* feat = (const float*)d_in[0];
    const float* rois = (const float*)d_in[1];
    float* out = (float*)d_out;

    const size_t fth_b   = (size_t)B_ * HW_ * C_ * sizeof(__half);    //  8,388,608
    const size_t slack_b = (size_t)SLACKH * sizeof(__half);           //      4,096
    const size_t perm_b  = (size_t)R_ * sizeof(int);                  //      4,096
    const size_t geom_b  = (size_t)R_ * PHW_ * GREC * sizeof(float);  //  3,211,264
    const size_t scr_b   = (size_t)R_ * PHW_ * C_ * sizeof(__half);   // 25,690,112

    if (ws_size >= fth_b + slack_b + perm_b + geom_b + scr_b) {
        __half* fTh  = (__half*)d_ws;
        int*    perm = (int*)((char*)d_ws + fth_b + slack_b);
        float*  geom = (float*)((char*)d_ws + fth_b + slack_b + perm_b);
        __half* scr  = (__half*)((char*)d_ws + fth_b + slack_b + perm_b + geom_b);
        prep<<<4293, 256, 0, stream>>>(feat, fTh, rois, perm, geom);
        prroi_bins<<<(R_ * PHW_) / 8, 512, 0, stream>>>(fTh, perm, geom, scr);
        fixup<<<R_, 256, 0, stream>>>(perm, scr, out);
    } else {
        prroi_pool_direct<<<R_ * PHW_, 256, 0, stream>>>(feat, rois, out);
    }
}

// Round 9
// 75.617 us; speedup vs baseline: 1.1260x; 1.1228x over previous
//
#include <hip/hip_runtime.h>
#include <hip/hip_fp16.h>

#define R_    1024
#define B_    4
#define C_    256
#define H_    64
#define W_    64
#define HW_   4096
#define PHW_  49
#define ROIT  128     // floats per per-ROI geometry record (512 B)
#define LROWF 258     // fixup LDS row halves (256 + 2 pad)

__device__ __forceinline__ void cell_w(float start, float end, float s, float& g0, float& g1) {
    float y0 = fmaxf(start, s);
    float yl = fmaxf(fminf(end, s + 1.0f), y0);
    float a  = y0 - s;
    float la = yl - s;
    g0 = la - 0.5f * la * la - a + 0.5f * a * a;
    g1 = 0.5f * la * la - 0.5f * a * a;
}

__device__ __forceinline__ float4 h4_to_f4(uint2 u) {
    __half2 a = *reinterpret_cast<__half2*>(&u.x);
    __half2 b = *reinterpret_cast<__half2*>(&u.y);
    float2 fa = __half22float2(a);
    float2 fb = __half22float2(b);
    return make_float4(fa.x, fa.y, fb.x, fb.y);
}

// ---- prep: transpose (B,C,H,W) f32 -> (B,H*W,C) f16 [0..4095]
//            + ROI sort [4096] + per-ROI geometry records [4097..4292] ----
// roitab[r] layout (floats, stride ROIT):
//   [0..48]   wx[pw][dx] raw (pw-major), zeroed beyond npx
//   [49+pw]   int: d_pw = w0_pw - w00
//   [63]      int: bb | w00<<8 | jlim<<16
//   [64+ph]   int: h0_ph | npy_ph<<8
//   [72+ph*8+t] wy[ph][t] * invwin, zeroed beyond npy
__global__ __launch_bounds__(256) void prep(const float* __restrict__ in,
                                            __half* __restrict__ fTh,
                                            const float* __restrict__ rois,
                                            int* __restrict__ perm,
                                            float* __restrict__ roitab) {
    int bid = blockIdx.x;
    if (bid < 4096) {
        __shared__ float tile[32][33];
        int b   = bid >> 10;
        int rem = bid & 1023;
        int c0  = (rem >> 7) * 32;
        int p0  = (rem & 127) * 32;
        int tx  = threadIdx.x & 31;
        int ty  = threadIdx.x >> 5;
        const float* src = in + (size_t)b * C_ * HW_;
#pragma unroll
        for (int i = 0; i < 32; i += 8)
            tile[ty + i][tx] = src[(size_t)(c0 + ty + i) * HW_ + (p0 + tx)];
        __syncthreads();
        __half2* dsth = (__half2*)(fTh + (size_t)b * HW_ * C_);
#pragma unroll
        for (int i = 0; i < 2; ++i) {
            int idx = threadIdx.x + i * 256;
            int py  = idx >> 4;
            int cp  = idx & 15;
            float lo = tile[cp * 2][py];
            float hi = tile[cp * 2 + 1][py];
            dsth[(size_t)(p0 + py) * (C_ / 2) + (c0 >> 1) + cp] = __floats2half2_rn(lo, hi);
        }
        return;
    }
    if (bid == 4096) {
        if (threadIdx.x >= 64) return;
        // 1 wave: ballot-based stable counting sort by (batch, y-band). Deterministic.
        int lane = threadIdx.x;
        unsigned long long below = (1ull << lane) - 1ull;
        int key[16];
#pragma unroll
        for (int i = 0; i < 16; ++i) {
            int idx = i * 64 + lane;
            const float* roi = rois + idx * 5;
            int b = (int)roi[0];
            float yc = (roi[2] + roi[4]) * 0.5f * 0.0625f;
            int yb = min(3, max(0, (int)(yc * 0.0625f)));
            key[i] = b * 4 + yb;
        }
        int cnt[16];
#pragma unroll
        for (int k = 0; k < 16; ++k) cnt[k] = 0;
        for (int i = 0; i < 16; ++i)
#pragma unroll
            for (int k = 0; k < 16; ++k)
                cnt[k] += __popcll(__ballot(key[i] == k));
        int off[16]; int acc = 0;
#pragma unroll
        for (int k = 0; k < 16; ++k) { off[k] = acc; acc += cnt[k]; }
        for (int i = 0; i < 16; ++i) {
#pragma unroll
            for (int k = 0; k < 16; ++k) {
                unsigned long long m = __ballot(key[i] == k);
                if (key[i] == k)
                    perm[off[k] + __popcll(m & below)] = i * 64 + lane;
                off[k] += __popcll(m);
            }
        }
        return;
    }
    // per-bin geometry -> scatter into per-ROI record
    int i = (bid - 4097) * 256 + threadIdx.x;   // 0..50175
    int r  = i / PHW_;
    int k  = i - r * PHW_;
    int ph = k / 7, pw = k - ph * 7;
    const float* roi = rois + r * 5;
    int bb = (int)roi[0];
    float x1 = roi[1] * 0.0625f, y1 = roi[2] * 0.0625f;
    float x2 = roi[3] * 0.0625f, y2 = roi[4] * 0.0625f;
    float rw = fmaxf(x2 - x1, 0.0f), rh = fmaxf(y2 - y1, 0.0f);
    float bw = rw / 7.0f, bh = rh / 7.0f;
    float win = bw * bh;
    float* rt = roitab + (size_t)r * ROIT;

    float wy[7], wx[7];
#pragma unroll
    for (int t = 0; t < 7; ++t) { wy[t] = 0.0f; wx[t] = 0.0f; }
    int w0 = 0, h0 = 0, npy = 0, w00 = 0;
    float invwin = 0.0f;
    if (win > 0.0f) {
        float ws = x1 + bw * (float)pw, we = ws + bw;
        float hs = y1 + bh * (float)ph, he = hs + bh;
        float s0w = floorf(ws), s0h = floorf(hs);
        w0 = (int)s0w; h0 = (int)s0h;
        w00 = (int)floorf(x1);
#pragma unroll
        for (int o = 0; o < 6; ++o) {
            float g0, g1;
            cell_w(hs, he, s0h + (float)o, g0, g1);
            wy[o] += g0; wy[o + 1] += g1;
            cell_w(ws, we, s0w + (float)o, g0, g1);
            wx[o] += g0; wx[o + 1] += g1;
        }
        npy = min(7, max(0, (int)ceilf(he - s0h + 1.0f)));
        int npx = min(7, max(0, (int)ceilf(we - s0w + 1.0f)));
        npy = max(0, min(npy, H_ - h0));
        npx = max(0, min(npx, W_ - w0));
#pragma unroll
        for (int t = 0; t < 7; ++t) {
            if (t >= npx) wx[t] = 0.0f;
            if (t >= npy) wy[t] = 0.0f;
        }
        invwin = 1.0f / win;
    }
    if (ph == 0) {
#pragma unroll
        for (int t = 0; t < 7; ++t) rt[pw * 7 + t] = wx[t];
        rt[49 + pw] = __int_as_float(w0 - w00);
    }
    if (pw == 0) {
#pragma unroll
        for (int t = 0; t < 7; ++t) rt[72 + ph * 8 + t] = wy[t] * invwin;
        rt[64 + ph] = __int_as_float(h0 | (npy << 8));
    }
    if (k == 0) {
        int jlim = 0;
        if (win > 0.0f) {
#pragma unroll
            for (int p = 0; p < 7; ++p) {
                float wsp = x1 + bw * (float)p, wep = wsp + bw;
                float s0wp = floorf(wsp);
                int w0p = (int)s0wp;
                int npxp = min(7, max(0, (int)ceilf(wep - s0wp + 1.0f)));
                npxp = max(0, min(npxp, W_ - w0p));
                jlim = max(jlim, (w0p - w00) + npxp);
            }
        }
        rt[63] = __int_as_float(bb | (w00 << 8) | (jlim << 16));
    }
}

// ---- compute: one wave per (ROI, bin-row). Column-streaming with shared LDS coef table.
__global__ __launch_bounds__(256) void prroi_rows(const __half* __restrict__ fTh,
                                                  const int* __restrict__ perm,
                                                  const float* __restrict__ roitab,
                                                  __half* __restrict__ scr) {
    __shared__ float colw[4][32 * 8];   // per-wave 32 cols x {7 coef + pad}
    int wid  = __builtin_amdgcn_readfirstlane(threadIdx.x >> 6);
    int lane = threadIdx.x & 63;
    int bid  = blockIdx.x;                         // 1792 blocks
    int g    = (bid & 7) * 896 + (bid >> 3) * 4 + wid;   // XCD-chunked 0..7167
    int rs   = g / 7;
    int ph   = g - rs * 7;
    int r    = __builtin_amdgcn_readfirstlane(perm[rs]);
    const float* rt = roitab + (size_t)r * ROIT;

    float* cwv = colw[wid];
#pragma unroll
    for (int t = 0; t < 4; ++t) cwv[lane + t * 64] = 0.0f;
    if (lane < 49) {
        int pw = lane / 7;
        int dx = lane - pw * 7;
        float wxv = rt[lane];
        int d = __float_as_int(rt[49 + pw]);
        cwv[(d + dx) * 8 + pw] = wxv;   // unique (jl,pw) per lane
    }
    int meta = __float_as_int(rt[63]);
    int bb   = meta & 0xff;
    int w00  = (meta >> 8) & 0xff;
    int jlim = (meta >> 16) & 0xff;
    int hm   = __float_as_int(rt[64 + ph]);
    int h0   = hm & 0xff;
    int npy  = (hm >> 8) & 0xff;

    float4 acc[7];
#pragma unroll
    for (int p = 0; p < 7; ++p) acc[p] = make_float4(0.f, 0.f, 0.f, 0.f);

    for (int dy = 0; dy < npy; ++dy) {             // wave-uniform bound
        float wyd = rt[72 + ph * 8 + dy];          // uniform -> scalar load
        const __half* rp = fTh + ((size_t)(bb * HW_ + (h0 + dy) * W_ + w00)) * C_ + lane * 4;
        float4 cacc[7];
#pragma unroll
        for (int p = 0; p < 7; ++p) cacc[p] = make_float4(0.f, 0.f, 0.f, 0.f);
        for (int jl = 0; jl < jlim; ++jl) {        // wave-uniform bound; 1 request/column
            uint2 v = *(const uint2*)(rp + (size_t)jl * C_);
            float4 f = h4_to_f4(v);
            const float* cw = cwv + jl * 8;
#pragma unroll
            for (int p = 0; p < 7; ++p) {
                float c = cw[p];                   // broadcast ds_read
                cacc[p].x = fmaf(c, f.x, cacc[p].x);
                cacc[p].y = fmaf(c, f.y, cacc[p].y);
                cacc[p].z = fmaf(c, f.z, cacc[p].z);
                cacc[p].w = fmaf(c, f.w, cacc[p].w);
            }
        }
#pragma unroll
        for (int p = 0; p < 7; ++p) {
            acc[p].x = fmaf(wyd, cacc[p].x, acc[p].x);
            acc[p].y = fmaf(wyd, cacc[p].y, acc[p].y);
            acc[p].z = fmaf(wyd, cacc[p].z, acc[p].z);
            acc[p].w = fmaf(wyd, cacc[p].w, acc[p].w);
        }
    }
    __half* sb = scr + ((size_t)r * PHW_ + ph * 7) * C_ + lane * 4;
#pragma unroll
    for (int p = 0; p < 7; ++p) {
        union { __half2 h2[2]; uint2 u; } pk2;
        pk2.h2[0] = __floats2half2_rn(acc[p].x, acc[p].y);
        pk2.h2[1] = __floats2half2_rn(acc[p].z, acc[p].w);
        *(uint2*)(sb + (size_t)p * C_) = pk2.u;
    }
}

// ---- fixup: per-ROI [k][c] f16 -> [c][k] f32 through padded LDS; XCD-matched ----
__global__ __launch_bounds__(256) void fixup(const int* __restrict__ perm,
                                             const __half* __restrict__ scr,
                                             float* __restrict__ out) {
    __shared__ __align__(4) __half lds_h[PHW_ * LROWF];
    int bid  = blockIdx.x;
    int spos = ((bid & 7) << 7) | (bid >> 3);
    int r    = perm[spos];
    const unsigned int* src = (const unsigned int*)(scr + (size_t)r * PHW_ * C_);
    for (int j = threadIdx.x; j < PHW_ * (C_ / 2); j += 256) {
        int row = j >> 7;
        int col = j & 127;
        *(unsigned int*)&lds_h[row * LROWF + col * 2] = src[j];
    }
    __syncthreads();
    float* outr = out + (size_t)r * (C_ * PHW_);
#pragma unroll 4
    for (int j = threadIdx.x; j < C_ * PHW_; j += 256) {
        int c = j / PHW_;
        int k = j - c * PHW_;
        outr[j] = __half2float(lds_h[k * LROWF + c]);
    }
}

// ---- fallback: original layout, no workspace ----
__global__ __launch_bounds__(256) void prroi_pool_direct(const float* __restrict__ f,
                                                         const float* __restrict__ rois,
                                                         float* __restrict__ out) {
    int bin = blockIdx.x;
    int r  = bin / PHW_;
    int k  = bin - r * PHW_;
    int ph = k / 7;
    int pw = k - ph * 7;
    int c = threadIdx.x;

    const float* roi = rois + r * 5;
    int bb = (int)roi[0];
    float x1 = roi[1] * 0.0625f, y1 = roi[2] * 0.0625f;
    float x2 = roi[3] * 0.0625f, y2 = roi[4] * 0.0625f;
    float rw = fmaxf(x2 - x1, 0.0f), rh = fmaxf(y2 - y1, 0.0f);
    float bw = rw / 7.0f, bh = rh / 7.0f;
    float win = bw * bh;
    size_t oidx = ((size_t)r * C_ + c) * PHW_ + k;
    if (!(win > 0.0f)) { out[oidx] = 0.0f; return; }

    float ws = x1 + bw * (float)pw, we = ws + bw;
    float hs = y1 + bh * (float)ph, he = hs + bh;
    float s0w = floorf(ws), s0h = floorf(hs);
    int w0 = (int)s0w, h0 = (int)s0h;
    float wy[7], wx[7];
#pragma unroll
    for (int t = 0; t < 7; ++t) { wy[t] = 0.0f; wx[t] = 0.0f; }
#pragma unroll
    for (int o = 0; o < 6; ++o) {
        float g0, g1;
        cell_w(hs, he, s0h + (float)o, g0, g1);
        wy[o] += g0; wy[o + 1] += g1;
        cell_w(ws, we, s0w + (float)o, g0, g1);
        wx[o] += g0; wx[o + 1] += g1;
    }
    int npy = min(7, max(0, (int)ceilf(he - s0h + 1.0f)));
    int npx = min(7, max(0, (int)ceilf(we - s0w + 1.0f)));
    npy = max(0, min(npy, H_ - h0));
    npx = max(0, min(npx, W_ - w0));

    const float* fbc = f + ((size_t)bb * C_ + c) * (H_ * W_);
    float acc = 0.0f;
#pragma unroll
    for (int dy = 0; dy < 7; ++dy) {
        if (dy < npy) {
            float row = 0.0f;
#pragma unroll
            for (int dx = 0; dx < 7; ++dx) {
                if (dx < npx)
                    row = fmaf(wx[dx], fbc[(h0 + dy) * W_ + (w0 + dx)], row);
            }
            acc = fmaf(wy[dy], row, acc);
        }
    }
    out[oidx] = acc / win;
}

extern "C" void kernel_launch(void* const* d_in, const int* in_sizes, int n_in,
                              void* d_out, int out_size, void* d_ws, size_t ws_size,
                              hipStream_t stream) {
    const float* feat = (const float*)d_in[0];
    const float* rois = (const float*)d_in[1];
    float* out = (float*)d_out;

    const size_t fth_b  = (size_t)B_ * HW_ * C_ * sizeof(__half);     //  8,388,608
    const size_t perm_b = (size_t)R_ * sizeof(int);                   //      4,096
    const size_t rt_b   = (size_t)R_ * ROIT * sizeof(float);          //    524,288
    const size_t scr_b  = (size_t)R_ * PHW_ * C_ * sizeof(__half);    // 25,690,112

    if (ws_size >= fth_b + perm_b + rt_b + scr_b) {
        __half* fTh  = (__half*)d_ws;
        int*    perm = (int*)((char*)d_ws + fth_b);
        float*  rtab = (float*)((char*)d_ws + fth_b + perm_b);
        __half* scr  = (__half*)((char*)d_ws + fth_b + perm_b + rt_b);
        prep<<<4293, 256, 0, stream>>>(feat, fTh, rois, perm, rtab);
        prroi_rows<<<(R_ * 7) / 4, 256, 0, stream>>>(fTh, perm, rtab, scr);
        fixup<<<R_, 256, 0, stream>>>(perm, scr, out);
    } else {
        prroi_pool_direct<<<R_ * PHW_, 256, 0, stream>>>(feat, rois, out);
    }
}